// Round 1
// baseline (626.365 us; speedup 1.0000x reference)
//
#include <hip/hip_runtime.h>
#include <hip/hip_bf16.h>

// GRU fused cell: B=32768, I=H=1024, fp32 in/out, bf16 MFMA internally.
#define B_ROWS 32768
#define KD     1024   // I == H == 1024 (K of all dot products)
#define HD     1024   // output width

#define BM 128        // block tile rows
#define BN 64         // block tile cols
#define BK 32         // K step (one 16x16x32 MFMA deep)
#define PK 40         // padded LDS K pitch (bf16 elems): 80B row pitch, spreads banks

typedef __bf16 bf16_t;
typedef __bf16 bf16x8 __attribute__((ext_vector_type(8)));
typedef __bf16 bf16x4 __attribute__((ext_vector_type(4)));
typedef float  f32x4  __attribute__((ext_vector_type(4)));

__device__ __forceinline__ float sigm_f(float v)  { return 1.0f / (1.0f + __expf(-v)); }
__device__ __forceinline__ float tanh_f(float v)  { return 2.0f / (1.0f + __expf(-2.0f * v)) - 1.0f; }

__device__ __forceinline__ bf16x4 cvt4(f32x4 v) {
    bf16x4 r;
    r[0] = (bf16_t)v[0]; r[1] = (bf16_t)v[1];
    r[2] = (bf16_t)v[2]; r[3] = (bf16_t)v[3];
    return r;
}

__global__ void __launch_bounds__(256, 2)
gru_fused_kernel(const float* __restrict__ x,  const float* __restrict__ h,
                 const float* __restrict__ w_ir, const float* __restrict__ w_hr,
                 const float* __restrict__ w_iz, const float* __restrict__ w_hz,
                 const float* __restrict__ w_in, const float* __restrict__ w_hn,
                 const float* __restrict__ b_ir, const float* __restrict__ b_hr,
                 const float* __restrict__ b_iz, const float* __restrict__ b_hz,
                 const float* __restrict__ b_in, const float* __restrict__ b_hn,
                 float* __restrict__ out)
{
    __shared__ __align__(16) bf16_t xs[BM][PK];
    __shared__ __align__(16) bf16_t hs[BM][PK];
    __shared__ __align__(16) bf16_t ws[6][BN][PK];

    const int tid  = threadIdx.x;
    const int lane = tid & 63;
    const int wid  = tid >> 6;     // 0..3
    const int wr   = wid >> 1;     // wave row: owns 64 rows
    const int wc   = wid & 1;      // wave col: owns 32 cols

    // N-fast ordering: 16 consecutive blocks share the same x/h slab (L2-hot),
    // weights (24 MB total) live in L2/L3 across M-groups.
    const int nblk = HD / BN;            // 16
    const int bidN = blockIdx.x % nblk;
    const int bidM = blockIdx.x / nblk;
    const int rowBase = bidM * BM;
    const int colBase = bidN * BN;

    const float* wptr[6] = { w_ir, w_hr, w_iz, w_hz, w_in, w_hn };

    // Staging geometry (constant per thread):
    // x/h tile: 128x32 fp32 = 1024 float4, 4 per thread. idx -> row=idx>>3, col4=idx&7.
    int sr[4], sc[4];
    #pragma unroll
    for (int i = 0; i < 4; ++i) {
        int idx = tid + i * 256;
        sr[i] = idx >> 3;
        sc[i] = (idx & 7) * 4;
    }
    int xoff[4];                         // element offsets into x / h (same shape)
    #pragma unroll
    for (int i = 0; i < 4; ++i) xoff[i] = (rowBase + sr[i]) * KD + sc[i];
    int woff[2];                         // weight tile: 64x32 = 512 float4, 2 per thread
    #pragma unroll
    for (int i = 0; i < 2; ++i) woff[i] = (colBase + sr[i]) * KD + sc[i];

    const f32x4 vzero = {0.f, 0.f, 0.f, 0.f};
    f32x4 accR[4][2], accZ[4][2], accIN[4][2], accHN[4][2];
    #pragma unroll
    for (int m = 0; m < 4; ++m)
        #pragma unroll
        for (int n = 0; n < 2; ++n) {
            accR[m][n] = vzero; accZ[m][n] = vzero;
            accIN[m][n] = vzero; accHN[m][n] = vzero;
        }

    const int fr = lane & 15;            // fragment row/col within 16
    const int ko = (lane >> 4) * 8;      // K sub-offset for A/B fragments

    for (int k0 = 0; k0 < KD; k0 += BK) {
        __syncthreads();   // previous iteration's fragment reads done

        // ---- stage x, h (fp32 -> bf16) ----
        #pragma unroll
        for (int i = 0; i < 4; ++i) {
            f32x4 vx = *(const f32x4*)&x[xoff[i] + k0];
            f32x4 vh = *(const f32x4*)&h[xoff[i] + k0];
            *(bf16x4*)&xs[sr[i]][sc[i]] = cvt4(vx);
            *(bf16x4*)&hs[sr[i]][sc[i]] = cvt4(vh);
        }
        // ---- stage 6 weight tiles ----
        #pragma unroll
        for (int g = 0; g < 6; ++g) {
            #pragma unroll
            for (int i = 0; i < 2; ++i) {
                f32x4 vw = *(const f32x4*)&wptr[g][woff[i] + k0];
                *(bf16x4*)&ws[g][sr[i]][sc[i]] = cvt4(vw);
            }
        }
        __syncthreads();

        // ---- fragments: lane reads 8 contiguous bf16 along K ----
        bf16x8 xa[4], ha[4];
        #pragma unroll
        for (int m = 0; m < 4; ++m) {
            xa[m] = *(const bf16x8*)&xs[wr * 64 + m * 16 + fr][ko];
            ha[m] = *(const bf16x8*)&hs[wr * 64 + m * 16 + fr][ko];
        }
        bf16x8 wb[6][2];
        #pragma unroll
        for (int g = 0; g < 6; ++g)
            #pragma unroll
            for (int n = 0; n < 2; ++n)
                wb[g][n] = *(const bf16x8*)&ws[g][wc * 32 + n * 16 + fr][ko];

        #pragma unroll
        for (int m = 0; m < 4; ++m) {
            #pragma unroll
            for (int n = 0; n < 2; ++n) {
                accR[m][n]  = __builtin_amdgcn_mfma_f32_16x16x32_bf16(xa[m], wb[0][n], accR[m][n], 0, 0, 0);
                accR[m][n]  = __builtin_amdgcn_mfma_f32_16x16x32_bf16(ha[m], wb[1][n], accR[m][n], 0, 0, 0);
                accZ[m][n]  = __builtin_amdgcn_mfma_f32_16x16x32_bf16(xa[m], wb[2][n], accZ[m][n], 0, 0, 0);
                accZ[m][n]  = __builtin_amdgcn_mfma_f32_16x16x32_bf16(ha[m], wb[3][n], accZ[m][n], 0, 0, 0);
                accIN[m][n] = __builtin_amdgcn_mfma_f32_16x16x32_bf16(xa[m], wb[4][n], accIN[m][n], 0, 0, 0);
                accHN[m][n] = __builtin_amdgcn_mfma_f32_16x16x32_bf16(ha[m], wb[5][n], accHN[m][n], 0, 0, 0);
            }
        }
    }

    // ---- fused epilogue ----
    // C/D layout (m89-verified): col = lane&15, row = (lane>>4)*4 + reg.
    const int rq = (lane >> 4) * 4;
    float br[2], bz[2], bi[2], bh[2];
    #pragma unroll
    for (int n = 0; n < 2; ++n) {
        int c = colBase + wc * 32 + n * 16 + fr;
        br[n] = b_ir[c] + b_hr[c];
        bz[n] = b_iz[c] + b_hz[c];
        bi[n] = b_in[c];
        bh[n] = b_hn[c];
    }
    #pragma unroll
    for (int m = 0; m < 4; ++m) {
        #pragma unroll
        for (int n = 0; n < 2; ++n) {
            int gc = colBase + wc * 32 + n * 16 + fr;
            #pragma unroll
            for (int j = 0; j < 4; ++j) {
                int gr = rowBase + wr * 64 + m * 16 + rq + j;
                float rv = sigm_f(accR[m][n][j] + br[n]);
                float zv = sigm_f(accZ[m][n][j] + bz[n]);
                float nv = tanh_f(accIN[m][n][j] + bi[n] + rv * (accHN[m][n][j] + bh[n]));
                float hv = h[gr * HD + gc];
                out[gr * HD + gc] = (1.0f - zv) * nv + zv * hv;
            }
        }
    }
}

extern "C" void kernel_launch(void* const* d_in, const int* in_sizes, int n_in,
                              void* d_out, int out_size, void* d_ws, size_t ws_size,
                              hipStream_t stream) {
    const float* x    = (const float*)d_in[0];
    const float* h    = (const float*)d_in[1];
    const float* w_ir = (const float*)d_in[2];
    const float* w_hr = (const float*)d_in[3];
    const float* w_iz = (const float*)d_in[4];
    const float* w_hz = (const float*)d_in[5];
    const float* w_in = (const float*)d_in[6];
    const float* w_hn = (const float*)d_in[7];
    const float* b_ir = (const float*)d_in[8];
    const float* b_hr = (const float*)d_in[9];
    const float* b_iz = (const float*)d_in[10];
    const float* b_hz = (const float*)d_in[11];
    const float* b_in = (const float*)d_in[12];
    const float* b_hn = (const float*)d_in[13];
    float* out = (float*)d_out;

    dim3 grid((B_ROWS / BM) * (HD / BN));   // 256 * 16 = 4096
    dim3 block(256);
    gru_fused_kernel<<<grid, block, 0, stream>>>(
        x, h, w_ir, w_hr, w_iz, w_hz, w_in, w_hn,
        b_ir, b_hr, b_iz, b_hz, b_in, b_hn, out);
}

// Round 3
// 519.979 us; speedup vs baseline: 1.2046x; 1.2046x over previous
//
#include <hip/hip_runtime.h>
#include <hip/hip_bf16.h>

// GRU fused cell: B=32768, I=H=1024, fp32 in/out, bf16 MFMA internally.
// R3: R2 structure with cvt_kernel x/h decode fixed (512 slots per 8KB chunk,
// was wrongly 1024 -> scrambled staging image).

#define B_ROWS 32768
#define KD     1024
#define HD     1024

#define BM 128
#define BN 64
#define BK 32

typedef __bf16 bf16_t;
typedef __bf16 bf16x8 __attribute__((ext_vector_type(8)));
typedef __bf16 bf16x4 __attribute__((ext_vector_type(4)));
typedef float  f32x4  __attribute__((ext_vector_type(4)));

// ---- d_ws layout (all bf16) ----
// x_t: [0, 64MB):    [Mtile 256][Kt 32][row 128][slot 4][8]   (8 KB chunks, 512 slots)
// h_t: [64MB,128MB): same
// w_t: [128MB,140MB):[Ntile 16][Kt 32][gate 6][row 64][slot 4][8] (24 KB chunks, 1536 slots)
// phys slot s holds logical kslot (s ^ ((row>>1)&3))  -> swizzled LDS image.
#define XT_BYTES  67108864ull
#define WT_OFF   134217728ull
#define WS_NEEDED 146800640ull

#define X_SLOTS 4194304   // 32768*1024*2B / 16B
#define W_BASE_SLOT 8388608
#define TOTAL_SLOTS 9175040

__device__ __forceinline__ float sigm_f(float v) { return 1.0f / (1.0f + __expf(-v)); }
__device__ __forceinline__ float tanh_f(float v) { return 2.0f / (1.0f + __expf(-2.0f * v)) - 1.0f; }

__device__ __forceinline__ bf16x4 cvt4(f32x4 v) {
    bf16x4 r;
    r[0] = (bf16_t)v[0]; r[1] = (bf16_t)v[1];
    r[2] = (bf16_t)v[2]; r[3] = (bf16_t)v[3];
    return r;
}

__device__ __forceinline__ void glds16(const void* g, void* l) {
    __builtin_amdgcn_global_load_lds(
        (const __attribute__((address_space(1))) void*)g,
        (__attribute__((address_space(3))) void*)l, 16, 0, 0);
}

struct WPtrs { const float* p[6]; };

// ---------------- conversion / relayout pre-pass ----------------
__global__ void __launch_bounds__(256)
cvt_kernel(const float* __restrict__ x, const float* __restrict__ h,
           WPtrs wp, bf16_t* __restrict__ ws)
{
    int sid = blockIdx.x * 256 + threadIdx.x;
    if (sid >= TOTAL_SLOTS) return;

    const float* src;
    if (sid < W_BASE_SLOT) {
        const float* base = (sid < X_SLOTS) ? x : h;
        int s2   = sid & (X_SLOTS - 1);
        int tile = s2 >> 9;             // 512 slots per 8KB chunk (128 rows x 4 slots)
        int c    = s2 & 511;
        int row  = c >> 2, s = c & 3;
        int mt   = tile >> 5, kt = tile & 31;
        int ks   = s ^ ((row >> 1) & 3);
        src = base + (size_t)(mt * 128 + row) * KD + kt * 32 + ks * 8;
    } else {
        int s2   = sid - W_BASE_SLOT;
        int tile = s2 / 1536;           // 1536 slots per 24KB chunk (6 gates x 64 rows x 4)
        int c    = s2 % 1536;
        int g    = c >> 8;
        int cc   = c & 255;
        int row  = cc >> 2, s = cc & 3;
        int nt   = tile >> 5, kt = tile & 31;
        int ks   = s ^ ((row >> 1) & 3);
        src = wp.p[g] + (size_t)(nt * 64 + row) * KD + kt * 32 + ks * 8;
    }
    f32x4 a = *(const f32x4*)src;
    f32x4 b = *(const f32x4*)(src + 4);
    bf16x8 o;
    o[0]=(bf16_t)a[0]; o[1]=(bf16_t)a[1]; o[2]=(bf16_t)a[2]; o[3]=(bf16_t)a[3];
    o[4]=(bf16_t)b[0]; o[5]=(bf16_t)b[1]; o[6]=(bf16_t)b[2]; o[7]=(bf16_t)b[3];
    *(bf16x8*)(ws + (size_t)sid * 8) = o;
}

// ---------------- fused MFMA GEMM + GRU epilogue ----------------
__global__ void __launch_bounds__(256, 2)
gru_mfma_kernel(const bf16_t* __restrict__ xt, const bf16_t* __restrict__ ht,
                const bf16_t* __restrict__ wt,
                const float* __restrict__ h,
                const float* __restrict__ b_ir, const float* __restrict__ b_hr,
                const float* __restrict__ b_iz, const float* __restrict__ b_hz,
                const float* __restrict__ b_in, const float* __restrict__ b_hn,
                float* __restrict__ out)
{
    __shared__ __align__(16) char smem[40960];   // xs 8K | hs 8K | ws 24K

    const int tid  = threadIdx.x;
    const int lane = tid & 63;
    const int wid  = tid >> 6;
    const int wr   = wid >> 1;
    const int wc   = wid & 1;

    const int nblk = HD / BN;                  // 16
    const int bidN = blockIdx.x % nblk;
    const int bidM = blockIdx.x / nblk;
    const int rowBase = bidM * BM;
    const int colBase = bidN * BN;

    const char* xcb = (const char*)xt + (size_t)bidM * 32 * 8192;
    const char* hcb = (const char*)ht + (size_t)bidM * 32 * 8192;
    const char* wcb = (const char*)wt + (size_t)bidN * 32 * 24576;

    const f32x4 vzero = {0.f, 0.f, 0.f, 0.f};
    f32x4 accR[4][2], accZ[4][2], accIN[4][2], accHN[4][2];
    #pragma unroll
    for (int m = 0; m < 4; ++m)
        #pragma unroll
        for (int n = 0; n < 2; ++n) {
            accR[m][n] = vzero; accZ[m][n] = vzero;
            accIN[m][n] = vzero; accHN[m][n] = vzero;
        }

    const int fr  = lane & 15;
    const int sl  = lane >> 4;
    const int f   = (fr >> 1) & 3;
    const int col = ((sl ^ f) << 4);           // swizzled 16B phys slot byte offset
    int aoff[4], boff[2];
    #pragma unroll
    for (int m = 0; m < 4; ++m) aoff[m] = (wr * 64 + m * 16 + fr) * 64 + col;
    #pragma unroll
    for (int n = 0; n < 2; ++n) boff[n] = (wc * 32 + n * 16 + fr) * 64 + col;

    for (int kt = 0; kt < 32; ++kt) {
        const char* xc = xcb + (size_t)kt * 8192;
        const char* hc = hcb + (size_t)kt * 8192;
        const char* wc2 = wcb + (size_t)kt * 24576;

        // stage: wave-uniform LDS dest + per-lane global src (linear image)
        #pragma unroll
        for (int i = 0; i < 2; ++i) {
            int off = wid * 2048 + i * 1024;
            glds16(xc + off + lane * 16, smem + off);
            glds16(hc + off + lane * 16, smem + 8192 + off);
        }
        #pragma unroll
        for (int j = 0; j < 6; ++j) {
            int off = wid * 6144 + j * 1024;
            glds16(wc2 + off + lane * 16, smem + 16384 + off);
        }
        __syncthreads();   // vmcnt(0) drain + barrier (compiler-emitted)

        bf16x8 xa[4], ha[4];
        #pragma unroll
        for (int m = 0; m < 4; ++m) {
            xa[m] = *(const bf16x8*)(smem + aoff[m]);
            ha[m] = *(const bf16x8*)(smem + 8192 + aoff[m]);
        }
        bf16x8 wb[6][2];
        #pragma unroll
        for (int g = 0; g < 6; ++g)
            #pragma unroll
            for (int n = 0; n < 2; ++n)
                wb[g][n] = *(const bf16x8*)(smem + 16384 + g * 4096 + boff[n]);

        #pragma unroll
        for (int m = 0; m < 4; ++m) {
            #pragma unroll
            for (int n = 0; n < 2; ++n) {
                accR[m][n]  = __builtin_amdgcn_mfma_f32_16x16x32_bf16(xa[m], wb[0][n], accR[m][n], 0, 0, 0);
                accR[m][n]  = __builtin_amdgcn_mfma_f32_16x16x32_bf16(ha[m], wb[1][n], accR[m][n], 0, 0, 0);
                accZ[m][n]  = __builtin_amdgcn_mfma_f32_16x16x32_bf16(xa[m], wb[2][n], accZ[m][n], 0, 0, 0);
                accZ[m][n]  = __builtin_amdgcn_mfma_f32_16x16x32_bf16(ha[m], wb[3][n], accZ[m][n], 0, 0, 0);
                accIN[m][n] = __builtin_amdgcn_mfma_f32_16x16x32_bf16(xa[m], wb[4][n], accIN[m][n], 0, 0, 0);
                accHN[m][n] = __builtin_amdgcn_mfma_f32_16x16x32_bf16(ha[m], wb[5][n], accHN[m][n], 0, 0, 0);
            }
        }
        __syncthreads();   // frag reads done before next stage overwrites
    }

    // ---- fused epilogue (C/D layout: col=lane&15, row=(lane>>4)*4+j) ----
    const int rq = (lane >> 4) * 4;
    float br[2], bz[2], bi[2], bh[2];
    #pragma unroll
    for (int n = 0; n < 2; ++n) {
        int c = colBase + wc * 32 + n * 16 + fr;
        br[n] = b_ir[c] + b_hr[c];
        bz[n] = b_iz[c] + b_hz[c];
        bi[n] = b_in[c];
        bh[n] = b_hn[c];
    }
    #pragma unroll
    for (int m = 0; m < 4; ++m) {
        #pragma unroll
        for (int n = 0; n < 2; ++n) {
            int gc = colBase + wc * 32 + n * 16 + fr;
            #pragma unroll
            for (int j = 0; j < 4; ++j) {
                int gr = rowBase + wr * 64 + m * 16 + rq + j;
                float rv = sigm_f(accR[m][n][j] + br[n]);
                float zv = sigm_f(accZ[m][n][j] + bz[n]);
                float nv = tanh_f(accIN[m][n][j] + bi[n] + rv * (accHN[m][n][j] + bh[n]));
                float hv = h[(size_t)gr * HD + gc];
                out[(size_t)gr * HD + gc] = (1.0f - zv) * nv + zv * hv;
            }
        }
    }
}

// ---------------- R1 fallback (fp32 inputs staged in-kernel) ----------------
#define PK 40
__global__ void __launch_bounds__(256, 2)
gru_fused_kernel(const float* __restrict__ x,  const float* __restrict__ h,
                 const float* __restrict__ w_ir, const float* __restrict__ w_hr,
                 const float* __restrict__ w_iz, const float* __restrict__ w_hz,
                 const float* __restrict__ w_in, const float* __restrict__ w_hn,
                 const float* __restrict__ b_ir, const float* __restrict__ b_hr,
                 const float* __restrict__ b_iz, const float* __restrict__ b_hz,
                 const float* __restrict__ b_in, const float* __restrict__ b_hn,
                 float* __restrict__ out)
{
    __shared__ __align__(16) bf16_t xs[BM][PK];
    __shared__ __align__(16) bf16_t hs[BM][PK];
    __shared__ __align__(16) bf16_t ws[6][BN][PK];

    const int tid  = threadIdx.x;
    const int lane = tid & 63;
    const int wid  = tid >> 6;
    const int wr   = wid >> 1;
    const int wc   = wid & 1;

    const int nblk = HD / BN;
    const int bidN = blockIdx.x % nblk;
    const int bidM = blockIdx.x / nblk;
    const int rowBase = bidM * BM;
    const int colBase = bidN * BN;

    const float* wptr[6] = { w_ir, w_hr, w_iz, w_hz, w_in, w_hn };

    int sr[4], sc[4];
    #pragma unroll
    for (int i = 0; i < 4; ++i) {
        int idx = tid + i * 256;
        sr[i] = idx >> 3;
        sc[i] = (idx & 7) * 4;
    }
    int xoff[4];
    #pragma unroll
    for (int i = 0; i < 4; ++i) xoff[i] = (rowBase + sr[i]) * KD + sc[i];
    int woff[2];
    #pragma unroll
    for (int i = 0; i < 2; ++i) woff[i] = (colBase + sr[i]) * KD + sc[i];

    const f32x4 vzero = {0.f, 0.f, 0.f, 0.f};
    f32x4 accR[4][2], accZ[4][2], accIN[4][2], accHN[4][2];
    #pragma unroll
    for (int m = 0; m < 4; ++m)
        #pragma unroll
        for (int n = 0; n < 2; ++n) {
            accR[m][n] = vzero; accZ[m][n] = vzero;
            accIN[m][n] = vzero; accHN[m][n] = vzero;
        }

    const int fr = lane & 15;
    const int ko = (lane >> 4) * 8;

    for (int k0 = 0; k0 < KD; k0 += BK) {
        __syncthreads();
        #pragma unroll
        for (int i = 0; i < 4; ++i) {
            f32x4 vx = *(const f32x4*)&x[xoff[i] + k0];
            f32x4 vh = *(const f32x4*)&h[xoff[i] + k0];
            *(bf16x4*)&xs[sr[i]][sc[i]] = cvt4(vx);
            *(bf16x4*)&hs[sr[i]][sc[i]] = cvt4(vh);
        }
        #pragma unroll
        for (int g = 0; g < 6; ++g) {
            #pragma unroll
            for (int i = 0; i < 2; ++i) {
                f32x4 vw = *(const f32x4*)&wptr[g][woff[i] + k0];
                *(bf16x4*)&ws[g][sr[i]][sc[i]] = cvt4(vw);
            }
        }
        __syncthreads();

        bf16x8 xa[4], ha[4];
        #pragma unroll
        for (int m = 0; m < 4; ++m) {
            xa[m] = *(const bf16x8*)&xs[wr * 64 + m * 16 + fr][ko];
            ha[m] = *(const bf16x8*)&hs[wr * 64 + m * 16 + fr][ko];
        }
        bf16x8 wb[6][2];
        #pragma unroll
        for (int g = 0; g < 6; ++g)
            #pragma unroll
            for (int n = 0; n < 2; ++n)
                wb[g][n] = *(const bf16x8*)&ws[g][wc * 32 + n * 16 + fr][ko];

        #pragma unroll
        for (int m = 0; m < 4; ++m) {
            #pragma unroll
            for (int n = 0; n < 2; ++n) {
                accR[m][n]  = __builtin_amdgcn_mfma_f32_16x16x32_bf16(xa[m], wb[0][n], accR[m][n], 0, 0, 0);
                accR[m][n]  = __builtin_amdgcn_mfma_f32_16x16x32_bf16(ha[m], wb[1][n], accR[m][n], 0, 0, 0);
                accZ[m][n]  = __builtin_amdgcn_mfma_f32_16x16x32_bf16(xa[m], wb[2][n], accZ[m][n], 0, 0, 0);
                accZ[m][n]  = __builtin_amdgcn_mfma_f32_16x16x32_bf16(ha[m], wb[3][n], accZ[m][n], 0, 0, 0);
                accIN[m][n] = __builtin_amdgcn_mfma_f32_16x16x32_bf16(xa[m], wb[4][n], accIN[m][n], 0, 0, 0);
                accHN[m][n] = __builtin_amdgcn_mfma_f32_16x16x32_bf16(ha[m], wb[5][n], accHN[m][n], 0, 0, 0);
            }
        }
    }

    const int rq = (lane >> 4) * 4;
    float br[2], bz[2], bi[2], bh[2];
    #pragma unroll
    for (int n = 0; n < 2; ++n) {
        int c = colBase + wc * 32 + n * 16 + fr;
        br[n] = b_ir[c] + b_hr[c];
        bz[n] = b_iz[c] + b_hz[c];
        bi[n] = b_in[c];
        bh[n] = b_hn[c];
    }
    #pragma unroll
    for (int m = 0; m < 4; ++m) {
        #pragma unroll
        for (int n = 0; n < 2; ++n) {
            int gc = colBase + wc * 32 + n * 16 + fr;
            #pragma unroll
            for (int j = 0; j < 4; ++j) {
                int gr = rowBase + wr * 64 + m * 16 + rq + j;
                float rv = sigm_f(accR[m][n][j] + br[n]);
                float zv = sigm_f(accZ[m][n][j] + bz[n]);
                float nv = tanh_f(accIN[m][n][j] + bi[n] + rv * (accHN[m][n][j] + bh[n]));
                float hv = h[gr * HD + gc];
                out[gr * HD + gc] = (1.0f - zv) * nv + zv * hv;
            }
        }
    }
}

extern "C" void kernel_launch(void* const* d_in, const int* in_sizes, int n_in,
                              void* d_out, int out_size, void* d_ws, size_t ws_size,
                              hipStream_t stream) {
    const float* x    = (const float*)d_in[0];
    const float* h    = (const float*)d_in[1];
    const float* w_ir = (const float*)d_in[2];
    const float* w_hr = (const float*)d_in[3];
    const float* w_iz = (const float*)d_in[4];
    const float* w_hz = (const float*)d_in[5];
    const float* w_in = (const float*)d_in[6];
    const float* w_hn = (const float*)d_in[7];
    const float* b_ir = (const float*)d_in[8];
    const float* b_hr = (const float*)d_in[9];
    const float* b_iz = (const float*)d_in[10];
    const float* b_hz = (const float*)d_in[11];
    const float* b_in = (const float*)d_in[12];
    const float* b_hn = (const float*)d_in[13];
    float* out = (float*)d_out;

    if (ws_size >= WS_NEEDED) {
        bf16_t* ws = (bf16_t*)d_ws;
        WPtrs wp;
        wp.p[0] = w_ir; wp.p[1] = w_hr; wp.p[2] = w_iz;
        wp.p[3] = w_hz; wp.p[4] = w_in; wp.p[5] = w_hn;
        cvt_kernel<<<(TOTAL_SLOTS + 255) / 256, 256, 0, stream>>>(x, h, wp, ws);

        const bf16_t* xt = ws;
        const bf16_t* ht = ws + XT_BYTES / 2;          // bf16 elements
        const bf16_t* wt = ws + WT_OFF / 2;
        dim3 grid((B_ROWS / BM) * (HD / BN));          // 4096
        gru_mfma_kernel<<<grid, 256, 0, stream>>>(
            xt, ht, wt, h, b_ir, b_hr, b_iz, b_hz, b_in, b_hn, out);
    } else {
        dim3 grid((B_ROWS / BM) * (HD / BN));
        gru_fused_kernel<<<grid, 256, 0, stream>>>(
            x, h, w_ir, w_hr, w_iz, w_hz, w_in, w_hn,
            b_ir, b_hr, b_iz, b_hz, b_in, b_hn, out);
    }
}

// Round 4
// 471.482 us; speedup vs baseline: 1.3285x; 1.1029x over previous
//
#include <hip/hip_runtime.h>
#include <hip/hip_bf16.h>

// GRU fused cell: B=32768, I=H=1024, fp32 in/out, bf16 MFMA internally.
// R4: double-buffered LDS + counted vmcnt(10) across raw s_barrier (T3+T4
// minimum schedule) — next tile's global_load_lds stays in flight during
// current tile's MFMA. No full vmcnt(0) drain inside the K-loop.

#define B_ROWS 32768
#define KD     1024
#define HD     1024

#define BM 128
#define BN 64
#define BK 32

typedef __bf16 bf16_t;
typedef __bf16 bf16x8 __attribute__((ext_vector_type(8)));
typedef __bf16 bf16x4 __attribute__((ext_vector_type(4)));
typedef float  f32x4  __attribute__((ext_vector_type(4)));

// ---- d_ws layout (all bf16) ----
// x_t: [0, 64MB):    [Mtile 256][Kt 32][row 128][slot 4][8]   (8 KB chunks, 512 slots)
// h_t: [64MB,128MB): same
// w_t: [128MB,140MB):[Ntile 16][Kt 32][gate 6][row 64][slot 4][8] (24 KB chunks, 1536 slots)
// phys slot s holds logical kslot (s ^ ((row>>1)&3))  -> swizzled LDS image.
#define XT_BYTES  67108864ull
#define WT_OFF   134217728ull
#define WS_NEEDED 146800640ull

#define X_SLOTS 4194304   // 32768*1024*2B / 16B
#define W_BASE_SLOT 8388608
#define TOTAL_SLOTS 9175040

__device__ __forceinline__ float sigm_f(float v) { return 1.0f / (1.0f + __expf(-v)); }
__device__ __forceinline__ float tanh_f(float v) { return 2.0f / (1.0f + __expf(-2.0f * v)) - 1.0f; }

__device__ __forceinline__ bf16x4 cvt4(f32x4 v) {
    bf16x4 r;
    r[0] = (bf16_t)v[0]; r[1] = (bf16_t)v[1];
    r[2] = (bf16_t)v[2]; r[3] = (bf16_t)v[3];
    return r;
}

__device__ __forceinline__ void glds16(const void* g, void* l) {
    __builtin_amdgcn_global_load_lds(
        (const __attribute__((address_space(1))) void*)g,
        (__attribute__((address_space(3))) void*)l, 16, 0, 0);
}

struct WPtrs { const float* p[6]; };

// ---------------- conversion / relayout pre-pass ----------------
__global__ void __launch_bounds__(256)
cvt_kernel(const float* __restrict__ x, const float* __restrict__ h,
           WPtrs wp, bf16_t* __restrict__ ws)
{
    int sid = blockIdx.x * 256 + threadIdx.x;
    if (sid >= TOTAL_SLOTS) return;

    const float* src;
    if (sid < W_BASE_SLOT) {
        const float* base = (sid < X_SLOTS) ? x : h;
        int s2   = sid & (X_SLOTS - 1);
        int tile = s2 >> 9;             // 512 slots per 8KB chunk (128 rows x 4 slots)
        int c    = s2 & 511;
        int row  = c >> 2, s = c & 3;
        int mt   = tile >> 5, kt = tile & 31;
        int ks   = s ^ ((row >> 1) & 3);
        src = base + (size_t)(mt * 128 + row) * KD + kt * 32 + ks * 8;
    } else {
        int s2   = sid - W_BASE_SLOT;
        int tile = s2 / 1536;           // 1536 slots per 24KB chunk (6 gates x 64 rows x 4)
        int c    = s2 % 1536;
        int g    = c >> 8;
        int cc   = c & 255;
        int row  = cc >> 2, s = cc & 3;
        int nt   = tile >> 5, kt = tile & 31;
        int ks   = s ^ ((row >> 1) & 3);
        src = wp.p[g] + (size_t)(nt * 64 + row) * KD + kt * 32 + ks * 8;
    }
    f32x4 a = *(const f32x4*)src;
    f32x4 b = *(const f32x4*)(src + 4);
    bf16x8 o;
    o[0]=(bf16_t)a[0]; o[1]=(bf16_t)a[1]; o[2]=(bf16_t)a[2]; o[3]=(bf16_t)a[3];
    o[4]=(bf16_t)b[0]; o[5]=(bf16_t)b[1]; o[6]=(bf16_t)b[2]; o[7]=(bf16_t)b[3];
    *(bf16x8*)(ws + (size_t)sid * 8) = o;
}

// ---------------- fused MFMA GEMM + GRU epilogue ----------------
__global__ void __launch_bounds__(256, 2)
gru_mfma_kernel(const bf16_t* __restrict__ xt, const bf16_t* __restrict__ ht,
                const bf16_t* __restrict__ wt,
                const float* __restrict__ h,
                const float* __restrict__ b_ir, const float* __restrict__ b_hr,
                const float* __restrict__ b_iz, const float* __restrict__ b_hz,
                const float* __restrict__ b_in, const float* __restrict__ b_hn,
                float* __restrict__ out)
{
    __shared__ __align__(16) char smem[2][40960];   // per buf: xs 8K | hs 8K | ws 24K

    const int tid  = threadIdx.x;
    const int lane = tid & 63;
    const int wid  = tid >> 6;
    const int wr   = wid >> 1;
    const int wc   = wid & 1;

    const int nblk = HD / BN;                  // 16
    const int bidN = blockIdx.x % nblk;
    const int bidM = blockIdx.x / nblk;
    const int rowBase = bidM * BM;
    const int colBase = bidN * BN;

    const char* xcb = (const char*)xt + (size_t)bidM * 32 * 8192;
    const char* hcb = (const char*)ht + (size_t)bidM * 32 * 8192;
    const char* wcb = (const char*)wt + (size_t)bidN * 32 * 24576;

    const f32x4 vzero = {0.f, 0.f, 0.f, 0.f};
    f32x4 accR[4][2], accZ[4][2], accIN[4][2], accHN[4][2];
    #pragma unroll
    for (int m = 0; m < 4; ++m)
        #pragma unroll
        for (int n = 0; n < 2; ++n) {
            accR[m][n] = vzero; accZ[m][n] = vzero;
            accIN[m][n] = vzero; accHN[m][n] = vzero;
        }

    const int fr  = lane & 15;
    const int sl  = lane >> 4;
    const int f   = (fr >> 1) & 3;
    const int col = ((sl ^ f) << 4);           // swizzled 16B phys slot byte offset
    int aoff[4], boff[2];
    #pragma unroll
    for (int m = 0; m < 4; ++m) aoff[m] = (wr * 64 + m * 16 + fr) * 64 + col;
    #pragma unroll
    for (int n = 0; n < 2; ++n) boff[n] = (wc * 32 + n * 16 + fr) * 64 + col;

    // issue one tile's staging loads (10 glds16 per wave)
    auto STAGE = [&](int buf, int kt) {
        const char* xc  = xcb + (size_t)kt * 8192;
        const char* hc  = hcb + (size_t)kt * 8192;
        const char* wc2 = wcb + (size_t)kt * 24576;
        char* s = smem[buf];
        #pragma unroll
        for (int i = 0; i < 2; ++i) {
            int off = wid * 2048 + i * 1024;
            glds16(xc + off + lane * 16, s + off);
            glds16(hc + off + lane * 16, s + 8192 + off);
        }
        #pragma unroll
        for (int j = 0; j < 6; ++j) {
            int off = wid * 6144 + j * 1024;
            glds16(wc2 + off + lane * 16, s + 16384 + off);
        }
    };

    auto COMPUTE = [&](const char* s) {
        bf16x8 xa[4], ha[4];
        #pragma unroll
        for (int m = 0; m < 4; ++m) {
            xa[m] = *(const bf16x8*)(s + aoff[m]);
            ha[m] = *(const bf16x8*)(s + 8192 + aoff[m]);
        }
        bf16x8 wb[6][2];
        #pragma unroll
        for (int g = 0; g < 6; ++g)
            #pragma unroll
            for (int n = 0; n < 2; ++n)
                wb[g][n] = *(const bf16x8*)(s + 16384 + g * 4096 + boff[n]);

        #pragma unroll
        for (int m = 0; m < 4; ++m) {
            #pragma unroll
            for (int n = 0; n < 2; ++n) {
                accR[m][n]  = __builtin_amdgcn_mfma_f32_16x16x32_bf16(xa[m], wb[0][n], accR[m][n], 0, 0, 0);
                accR[m][n]  = __builtin_amdgcn_mfma_f32_16x16x32_bf16(ha[m], wb[1][n], accR[m][n], 0, 0, 0);
                accZ[m][n]  = __builtin_amdgcn_mfma_f32_16x16x32_bf16(xa[m], wb[2][n], accZ[m][n], 0, 0, 0);
                accZ[m][n]  = __builtin_amdgcn_mfma_f32_16x16x32_bf16(ha[m], wb[3][n], accZ[m][n], 0, 0, 0);
                accIN[m][n] = __builtin_amdgcn_mfma_f32_16x16x32_bf16(xa[m], wb[4][n], accIN[m][n], 0, 0, 0);
                accHN[m][n] = __builtin_amdgcn_mfma_f32_16x16x32_bf16(ha[m], wb[5][n], accHN[m][n], 0, 0, 0);
            }
        }
    };

    STAGE(0, 0);                                   // prologue: tile 0 in flight

    for (int kt = 0; kt < 31; ++kt) {
        STAGE((kt + 1) & 1, kt + 1);               // prefetch next tile (10 loads)
        // wait for tile kt's 10 loads (older); leave tile kt+1's 10 in flight
        asm volatile("s_waitcnt vmcnt(10)" ::: "memory");
        __builtin_amdgcn_s_barrier();              // all waves: buf[kt&1] ready
        __builtin_amdgcn_sched_barrier(0);
        COMPUTE(smem[kt & 1]);
        __builtin_amdgcn_sched_barrier(0);
        __builtin_amdgcn_s_barrier();              // all waves done reading buf[kt&1]
    }
    asm volatile("s_waitcnt vmcnt(0)" ::: "memory");
    __builtin_amdgcn_s_barrier();
    __builtin_amdgcn_sched_barrier(0);
    COMPUTE(smem[1]);                              // tile 31

    // ---- fused epilogue (C/D layout: col=lane&15, row=(lane>>4)*4+j) ----
    const int rq = (lane >> 4) * 4;
    float br[2], bz[2], bi[2], bh[2];
    #pragma unroll
    for (int n = 0; n < 2; ++n) {
        int c = colBase + wc * 32 + n * 16 + fr;
        br[n] = b_ir[c] + b_hr[c];
        bz[n] = b_iz[c] + b_hz[c];
        bi[n] = b_in[c];
        bh[n] = b_hn[c];
    }
    #pragma unroll
    for (int m = 0; m < 4; ++m) {
        #pragma unroll
        for (int n = 0; n < 2; ++n) {
            int gc = colBase + wc * 32 + n * 16 + fr;
            #pragma unroll
            for (int j = 0; j < 4; ++j) {
                int gr = rowBase + wr * 64 + m * 16 + rq + j;
                float rv = sigm_f(accR[m][n][j] + br[n]);
                float zv = sigm_f(accZ[m][n][j] + bz[n]);
                float nv = tanh_f(accIN[m][n][j] + bi[n] + rv * (accHN[m][n][j] + bh[n]));
                float hv = h[(size_t)gr * HD + gc];
                out[(size_t)gr * HD + gc] = (1.0f - zv) * nv + zv * hv;
            }
        }
    }
}

// ---------------- R1 fallback (fp32 inputs staged in-kernel) ----------------
#define PK 40
__global__ void __launch_bounds__(256, 2)
gru_fused_kernel(const float* __restrict__ x,  const float* __restrict__ h,
                 const float* __restrict__ w_ir, const float* __restrict__ w_hr,
                 const float* __restrict__ w_iz, const float* __restrict__ w_hz,
                 const float* __restrict__ w_in, const float* __restrict__ w_hn,
                 const float* __restrict__ b_ir, const float* __restrict__ b_hr,
                 const float* __restrict__ b_iz, const float* __restrict__ b_hz,
                 const float* __restrict__ b_in, const float* __restrict__ b_hn,
                 float* __restrict__ out)
{
    __shared__ __align__(16) bf16_t xs[BM][PK];
    __shared__ __align__(16) bf16_t hs[BM][PK];
    __shared__ __align__(16) bf16_t ws[6][BN][PK];

    const int tid  = threadIdx.x;
    const int lane = tid & 63;
    const int wid  = tid >> 6;
    const int wr   = wid >> 1;
    const int wc   = wid & 1;

    const int nblk = HD / BN;
    const int bidN = blockIdx.x % nblk;
    const int bidM = blockIdx.x / nblk;
    const int rowBase = bidM * BM;
    const int colBase = bidN * BN;

    const float* wptr[6] = { w_ir, w_hr, w_iz, w_hz, w_in, w_hn };

    int sr[4], sc[4];
    #pragma unroll
    for (int i = 0; i < 4; ++i) {
        int idx = tid + i * 256;
        sr[i] = idx >> 3;
        sc[i] = (idx & 7) * 4;
    }
    int xoff[4];
    #pragma unroll
    for (int i = 0; i < 4; ++i) xoff[i] = (rowBase + sr[i]) * KD + sc[i];
    int woff[2];
    #pragma unroll
    for (int i = 0; i < 2; ++i) woff[i] = (colBase + sr[i]) * KD + sc[i];

    const f32x4 vzero = {0.f, 0.f, 0.f, 0.f};
    f32x4 accR[4][2], accZ[4][2], accIN[4][2], accHN[4][2];
    #pragma unroll
    for (int m = 0; m < 4; ++m)
        #pragma unroll
        for (int n = 0; n < 2; ++n) {
            accR[m][n] = vzero; accZ[m][n] = vzero;
            accIN[m][n] = vzero; accHN[m][n] = vzero;
        }

    const int fr = lane & 15;
    const int ko = (lane >> 4) * 8;

    for (int k0 = 0; k0 < KD; k0 += BK) {
        __syncthreads();
        #pragma unroll
        for (int i = 0; i < 4; ++i) {
            f32x4 vx = *(const f32x4*)&x[xoff[i] + k0];
            f32x4 vh = *(const f32x4*)&h[xoff[i] + k0];
            *(bf16x4*)&xs[sr[i]][sc[i]] = cvt4(vx);
            *(bf16x4*)&hs[sr[i]][sc[i]] = cvt4(vh);
        }
        #pragma unroll
        for (int g = 0; g < 6; ++g) {
            #pragma unroll
            for (int i = 0; i < 2; ++i) {
                f32x4 vw = *(const f32x4*)&wptr[g][woff[i] + k0];
                *(bf16x4*)&ws[g][sr[i]][sc[i]] = cvt4(vw);
            }
        }
        __syncthreads();

        bf16x8 xa[4], ha[4];
        #pragma unroll
        for (int m = 0; m < 4; ++m) {
            xa[m] = *(const bf16x8*)&xs[wr * 64 + m * 16 + fr][ko];
            ha[m] = *(const bf16x8*)&hs[wr * 64 + m * 16 + fr][ko];
        }
        bf16x8 wb[6][2];
        #pragma unroll
        for (int g = 0; g < 6; ++g)
            #pragma unroll
            for (int n = 0; n < 2; ++n)
                wb[g][n] = *(const bf16x8*)&ws[g][wc * 32 + n * 16 + fr][ko];

        #pragma unroll
        for (int m = 0; m < 4; ++m) {
            #pragma unroll
            for (int n = 0; n < 2; ++n) {
                accR[m][n]  = __builtin_amdgcn_mfma_f32_16x16x32_bf16(xa[m], wb[0][n], accR[m][n], 0, 0, 0);
                accR[m][n]  = __builtin_amdgcn_mfma_f32_16x16x32_bf16(ha[m], wb[1][n], accR[m][n], 0, 0, 0);
                accZ[m][n]  = __builtin_amdgcn_mfma_f32_16x16x32_bf16(xa[m], wb[2][n], accZ[m][n], 0, 0, 0);
                accZ[m][n]  = __builtin_amdgcn_mfma_f32_16x16x32_bf16(ha[m], wb[3][n], accZ[m][n], 0, 0, 0);
                accIN[m][n] = __builtin_amdgcn_mfma_f32_16x16x32_bf16(xa[m], wb[4][n], accIN[m][n], 0, 0, 0);
                accHN[m][n] = __builtin_amdgcn_mfma_f32_16x16x32_bf16(ha[m], wb[5][n], accHN[m][n], 0, 0, 0);
            }
        }
    }

    const int rq = (lane >> 4) * 4;
    float br[2], bz[2], bi[2], bh[2];
    #pragma unroll
    for (int n = 0; n < 2; ++n) {
        int c = colBase + wc * 32 + n * 16 + fr;
        br[n] = b_ir[c] + b_hr[c];
        bz[n] = b_iz[c] + b_hz[c];
        bi[n] = b_in[c];
        bh[n] = b_hn[c];
    }
    #pragma unroll
    for (int m = 0; m < 4; ++m) {
        #pragma unroll
        for (int n = 0; n < 2; ++n) {
            int gc = colBase + wc * 32 + n * 16 + fr;
            #pragma unroll
            for (int j = 0; j < 4; ++j) {
                int gr = rowBase + wr * 64 + m * 16 + rq + j;
                float rv = sigm_f(accR[m][n][j] + br[n]);
                float zv = sigm_f(accZ[m][n][j] + bz[n]);
                float nv = tanh_f(accIN[m][n][j] + bi[n] + rv * (accHN[m][n][j] + bh[n]));
                float hv = h[gr * HD + gc];
                out[gr * HD + gc] = (1.0f - zv) * nv + zv * hv;
            }
        }
    }
}

extern "C" void kernel_launch(void* const* d_in, const int* in_sizes, int n_in,
                              void* d_out, int out_size, void* d_ws, size_t ws_size,
                              hipStream_t stream) {
    const float* x    = (const float*)d_in[0];
    const float* h    = (const float*)d_in[1];
    const float* w_ir = (const float*)d_in[2];
    const float* w_hr = (const float*)d_in[3];
    const float* w_iz = (const float*)d_in[4];
    const float* w_hz = (const float*)d_in[5];
    const float* w_in = (const float*)d_in[6];
    const float* w_hn = (const float*)d_in[7];
    const float* b_ir = (const float*)d_in[8];
    const float* b_hr = (const float*)d_in[9];
    const float* b_iz = (const float*)d_in[10];
    const float* b_hz = (const float*)d_in[11];
    const float* b_in = (const float*)d_in[12];
    const float* b_hn = (const float*)d_in[13];
    float* out = (float*)d_out;

    if (ws_size >= WS_NEEDED) {
        bf16_t* ws = (bf16_t*)d_ws;
        WPtrs wp;
        wp.p[0] = w_ir; wp.p[1] = w_hr; wp.p[2] = w_iz;
        wp.p[3] = w_hz; wp.p[4] = w_in; wp.p[5] = w_hn;
        cvt_kernel<<<(TOTAL_SLOTS + 255) / 256, 256, 0, stream>>>(x, h, wp, ws);

        const bf16_t* xt = ws;
        const bf16_t* ht = ws + XT_BYTES / 2;          // bf16 elements
        const bf16_t* wt = ws + WT_OFF / 2;
        dim3 grid((B_ROWS / BM) * (HD / BN));          // 4096
        gru_mfma_kernel<<<grid, 256, 0, stream>>>(
            xt, ht, wt, h, b_ir, b_hr, b_iz, b_hz, b_in, b_hn, out);
    } else {
        dim3 grid((B_ROWS / BM) * (HD / BN));
        gru_fused_kernel<<<grid, 256, 0, stream>>>(
            x, h, w_ir, w_hr, w_iz, w_hz, w_in, w_hn,
            b_ir, b_hr, b_iz, b_hz, b_in, b_hn, out);
    }
}